// Round 10
// baseline (708.024 us; speedup 1.0000x reference)
//
#include <hip/hip_runtime.h>
#include <math.h>

// Problem constants
#define NTOK   32768       // B*S
#define D      2048        // N_EMBED
#define E      64          // NUM_EXPERTS
#define TOPK   8

#define BLOCK  256
#define TM     64          // tokens per block
#define BK     32          // K per chunk == MFMA K
#define NCHUNK (D / BK)    // 64
#define NBLK   (NTOK / TM) // 512

// w_bf layout in d_ws: per chunk c (16384 B): hi frags [0,8192), lo frags [8192,16384)
#define WBF_BYTES (NCHUNK * 16384)   // 1 MiB

// workspace map
#define FLAGS_OFF   WBF_BYTES                         // 8 B counter + tie-token list (16384 ints)
#define PAIR_OFF    (FLAGS_OFF + 65544)               // 512 ints: per-tb arrival counters
#define PART_OFF    (WBF_BYTES + 131072)              // fp32 partial logits [2][NTOK][128]
#define PART_BYTES  ((size_t)2 * NTOK * 128 * 4)      // 32 MiB
#define SKIPP_OFF   (PART_OFF + PART_BYTES)           // fp32 skip partials [2][NTOK]
#define SKIPP_BYTES ((size_t)2 * NTOK * 4)
#define WS_NEED     (SKIPP_OFF + SKIPP_BYTES)

#define LG_STR 133
#define SP_OFF  34048      // bytes (fallback kernel only)
#define SMEM_BYTES 34304

// r8 verified: 3e-4 band -> fixup out of top-5, absmax 0.0156 (passes).
#define TIE_EPS 3e-4f

typedef __bf16 bf16x8 __attribute__((ext_vector_type(8)));
typedef __bf16 bf16x2 __attribute__((ext_vector_type(2)));
typedef float  f32x4  __attribute__((ext_vector_type(4)));

__device__ __forceinline__ unsigned short f2bf_rne(float f) {
    unsigned int u = __float_as_uint(f);
    u += 0x7FFFu + ((u >> 16) & 1u);
    return (unsigned short)(u >> 16);
}

// v1: manual bit-twiddle pack (convert_w + fallback kernel, verified)
__device__ __forceinline__ void split_pack8(const float* xv, uint4& hv, uint4& lv) {
    unsigned int h[8], l[8];
#pragma unroll
    for (int j = 0; j < 8; ++j) {
        unsigned short hb = f2bf_rne(xv[j]);
        float hf = __uint_as_float(((unsigned int)hb) << 16);
        unsigned short lb = f2bf_rne(xv[j] - hf);
        h[j] = hb; l[j] = lb;
    }
    hv.x = h[0] | (h[1] << 16); hv.y = h[2] | (h[3] << 16);
    hv.z = h[4] | (h[5] << 16); hv.w = h[6] | (h[7] << 16);
    lv.x = l[0] | (l[1] << 16); lv.y = l[2] | (l[3] << 16);
    lv.z = l[4] | (l[5] << 16); lv.w = l[6] | (l[7] << 16);
}

// v2: native casts -> v_cvt_pk_bf16_f32 (RNE, bit-identical to v1)
__device__ __forceinline__ unsigned int pk2(float a, float b) {
    bf16x2 p;
    p[0] = (__bf16)a; p[1] = (__bf16)b;
    return __builtin_bit_cast(unsigned int, p);
}
__device__ __forceinline__ void split_pack8_v2(const float* xv, uint4& hv, uint4& lv) {
    unsigned int h[4], l[4];
#pragma unroll
    for (int p = 0; p < 4; ++p) {
        float a = xv[2 * p], b = xv[2 * p + 1];
        unsigned int hu = pk2(a, b);
        float fa = __uint_as_float(hu << 16);
        float fb = __uint_as_float(hu & 0xFFFF0000u);
        h[p] = hu;
        l[p] = pk2(a - fa, b - fb);
    }
    hv.x = h[0]; hv.y = h[1]; hv.z = h[2]; hv.w = h[3];
    lv.x = l[0]; lv.y = l[1]; lv.z = l[2]; lv.w = l[3];
}

// ---------------- pre-kernel: convert W (router||noise) to split-bf16 fragment layout ----------
__global__ __launch_bounds__(256) void convert_w_kernel(
    const float* __restrict__ wr, const float* __restrict__ wn, char* __restrict__ wbf)
{
    int u = blockIdx.x * 256 + threadIdx.x;
    int col  = u & 127;
    int koct = (u >> 7) & 3;
    int c    = u >> 9;
    const float* src = (col < 64)
        ? (wr + (size_t)(c * BK + koct * 8) * E + col)
        : (wn + (size_t)(c * BK + koct * 8) * E + (col - 64));
    float xv[8];
#pragma unroll
    for (int j = 0; j < 8; ++j) xv[j] = src[(size_t)j * E];
    uint4 hv, lv;
    split_pack8(xv, hv, lv);
    char* dst = wbf + (size_t)c * 16384 + (size_t)(koct * 128 + col) * 16;
    *(uint4*)dst = hv;
    *(uint4*)(dst + 8192) = lv;
}

// ---------------- gemm_fused: K-split MFMA + second-arriver combine + epilogue -----------------
// grid = 1024: kp = bid&1 (K half), tb = bid>>1 (64-token group).
// Both blocks of a tb-pair store their fp32 partial, fence, atomicAdd(pair[tb]).
// The SECOND arriver (old==1) still holds its half in acc registers: it reads only the partner's
// 32 KB, sums, and runs the full epilogue (hipCUB last-block-reduction pattern; deadlock-free,
// order-independent since one commutative fp add). Removes the combine dispatch + 32 MB of reads.
// LDS 34.3 KB -> 4 blocks/CU; VGPR ~100 (natural, r8) -> 4 waves/SIMD.
__global__ __launch_bounds__(BLOCK) void gemm_fused_kernel(
    const float* __restrict__ x, const char* __restrict__ wbf,
    const float* __restrict__ w_skip, const float* __restrict__ eps,
    const float* __restrict__ b_router, const float* __restrict__ b_noise,
    const float* __restrict__ b_skip,
    float* __restrict__ part, float* __restrict__ skip_part,
    float* __restrict__ out_router, float* __restrict__ out_idx,
    float* __restrict__ out_skip, int* __restrict__ flags,
    int* __restrict__ pair, int cap)
{
    __shared__ __attribute__((aligned(16))) float lg[TM * LG_STR];  // 34048 B
    __shared__ float sps[TM];                                       // own skip partials
    __shared__ int sOld;

    const int tid = threadIdx.x;
    const int kp  = blockIdx.x & 1;
    const int tb  = blockIdx.x >> 1;
    const int tokBase = tb * TM;
    const int c0 = kp * 32;

    const int lane = tid & 63;
    const int wv   = __builtin_amdgcn_readfirstlane(tid >> 6);
    const int tg   = wv >> 1;
    const int ch   = wv & 1;
    const int q    = lane >> 4;
    const int m    = lane & 15;

    const float* xlane  = x + (size_t)(tokBase + tg * 32 + m) * D + q * 8 + (size_t)c0 * BK;
    const char*  blane  = wbf + (size_t)((q << 7) + (ch << 6) + m) * 16 + (size_t)c0 * 16384;
    const float* wklane = w_skip + q * 8 + c0 * BK;

    f32x4 acc[2][4];
#pragma unroll
    for (int tt = 0; tt < 2; ++tt)
#pragma unroll
        for (int cw = 0; cw < 4; ++cw) acc[tt][cw] = (f32x4){0.f, 0.f, 0.f, 0.f};
    float skipAcc[2] = {0.f, 0.f};

    struct Gen {
        float4 a[2][2];
        uint4  b[4][2];
        float4 wk[2];
    };

    auto loadGen = [&](Gen& g, int c) {
        const float* xp = xlane + c * BK;
#pragma unroll
        for (int tt = 0; tt < 2; ++tt) {
            g.a[tt][0] = *(const float4*)(xp + (size_t)tt * 16 * D);
            g.a[tt][1] = *(const float4*)(xp + (size_t)tt * 16 * D + 4);
        }
        const char* bp = blane + (size_t)c * 16384;
#pragma unroll
        for (int cw = 0; cw < 4; ++cw) {
            g.b[cw][0] = *(const uint4*)(bp + cw * 256);
            g.b[cw][1] = *(const uint4*)(bp + cw * 256 + 8192);
        }
        g.wk[0] = *(const float4*)(wklane + c * BK);
        g.wk[1] = *(const float4*)(wklane + c * BK + 4);
    };

    auto computeGen = [&](Gen& g) {
#pragma unroll
        for (int tt = 0; tt < 2; ++tt) {
            float xv[8] = {g.a[tt][0].x, g.a[tt][0].y, g.a[tt][0].z, g.a[tt][0].w,
                           g.a[tt][1].x, g.a[tt][1].y, g.a[tt][1].z, g.a[tt][1].w};
            uint4 hv, lv;
            split_pack8_v2(xv, hv, lv);
            bf16x8 Ah = __builtin_bit_cast(bf16x8, hv);
            bf16x8 Al = __builtin_bit_cast(bf16x8, lv);
#pragma unroll
            for (int cw = 0; cw < 4; ++cw) {
                bf16x8 Bh = __builtin_bit_cast(bf16x8, g.b[cw][0]);
                bf16x8 Bl = __builtin_bit_cast(bf16x8, g.b[cw][1]);
                acc[tt][cw] = __builtin_amdgcn_mfma_f32_16x16x32_bf16(Ah, Bh, acc[tt][cw], 0, 0, 0);
                acc[tt][cw] = __builtin_amdgcn_mfma_f32_16x16x32_bf16(Ah, Bl, acc[tt][cw], 0, 0, 0);
                acc[tt][cw] = __builtin_amdgcn_mfma_f32_16x16x32_bf16(Al, Bh, acc[tt][cw], 0, 0, 0);
            }
            float s = skipAcc[tt];
            s = fmaf(xv[0], g.wk[0].x, s); s = fmaf(xv[1], g.wk[0].y, s);
            s = fmaf(xv[2], g.wk[0].z, s); s = fmaf(xv[3], g.wk[0].w, s);
            s = fmaf(xv[4], g.wk[1].x, s); s = fmaf(xv[5], g.wk[1].y, s);
            s = fmaf(xv[6], g.wk[1].z, s); s = fmaf(xv[7], g.wk[1].w, s);
            skipAcc[tt] = s;
        }
    };

    // ---- K loop over 32 chunks: register double-buffer, no barriers ----
    Gen gA, gB;
    loadGen(gA, 0);
#pragma unroll 1
    for (int c = 0; c < 32; c += 2) {
        loadGen(gB, c + 1);
        computeGen(gA);
        if (c + 2 < 32) loadGen(gA, c + 2);
        computeGen(gB);
    }

    // ---- persist partial logits (needed if the OTHER block finishes) ----
    float* pbase = part + (size_t)kp * NTOK * 128 + (size_t)tokBase * 128;
#pragma unroll
    for (int tt = 0; tt < 2; ++tt)
#pragma unroll
        for (int cw = 0; cw < 4; ++cw) {
#pragma unroll
            for (int reg = 0; reg < 4; ++reg) {
                int token = tg * 32 + tt * 16 + q * 4 + reg;
                int col = ch * 64 + cw * 16 + m;
                pbase[(size_t)token * 128 + col] = acc[tt][cw][reg];
            }
        }

    // skip reduce over the 4 k-octet lanes; persist + stash in LDS for the finisher role
#pragma unroll
    for (int tt = 0; tt < 2; ++tt) {
        skipAcc[tt] += __shfl_xor(skipAcc[tt], 16);
        skipAcc[tt] += __shfl_xor(skipAcc[tt], 32);
    }
    if (ch == 0 && lane < 16) {
        float* spg = skip_part + (size_t)kp * NTOK + tokBase + tg * 32;
        spg[lane]      = skipAcc[0];
        spg[16 + lane] = skipAcc[1];
        sps[tg * 32 + lane]      = skipAcc[0];
        sps[tg * 32 + 16 + lane] = skipAcc[1];
    }
    __syncthreads();                              // all stores issued (program order)

    if (tid == 0) {
        __threadfence();                          // release: flush partial to device scope
        sOld = atomicAdd(&pair[tb], 1);
    }
    __syncthreads();
    if (sOld != 1) return;                        // first arriver: done (uniform exit)

    if (tid == 0) __threadfence();                // acquire: invalidate before reading partner
    __syncthreads();

    // ---- finisher: combine partner half (global) with own half (registers) into LDS rows ----
    const int okp = kp ^ 1;
    const float* obase = part + (size_t)okp * NTOK * 128 + (size_t)tokBase * 128;
#pragma unroll
    for (int tt = 0; tt < 2; ++tt)
#pragma unroll
        for (int cw = 0; cw < 4; ++cw) {
#pragma unroll
            for (int reg = 0; reg < 4; ++reg) {
                int token = tg * 32 + tt * 16 + q * 4 + reg;
                int col = ch * 64 + cw * 16 + m;
                lg[token * LG_STR + col] =
                    acc[tt][cw][reg] + obase[(size_t)token * 128 + col];
            }
        }
    __syncthreads();

    // ---- epilogue: one lane per token (identical math to prior combine kernel) ----
    if (tid < 64) {
        const int t = tid;
        const int tok = tokBase + t;
        float* row = lg + t * LG_STR;

        float sv = sps[t] + skip_part[(size_t)okp * NTOK + tok] + b_skip[0];
        out_skip[tok] = 1.f / (1.f + expf(-sv));

        const float4* epsr = (const float4*)(eps + (size_t)tok * E);
#pragma unroll 4
        for (int e4 = 0; e4 < 16; ++e4) {
            float4 ep = epsr[e4];
            float epv[4] = {ep.x, ep.y, ep.z, ep.w};
#pragma unroll
            for (int u2 = 0; u2 < 4; ++u2) {
                int e = e4 * 4 + u2;
                float lgv = row[e] + b_router[e];
                float nl  = row[64 + e] + b_noise[e];
                float sp  = fmaxf(nl, 0.f) + log1pf(expf(-fabsf(nl)));
                row[e] = lgv + epv[u2] * sp;
            }
        }

        // top-9 (strict '>' => lowest index wins ties; matches lax.top_k)
        float vals[9];
        int idxs[8];
        for (int p = 0; p < 9; ++p) {
            float best = -INFINITY;
            int bi = 0;
            for (int e = 0; e < 64; ++e) {
                float v = row[e];
                if (v > best) { best = v; bi = e; }
            }
            vals[p] = best;
            if (p < 8) idxs[p] = bi;
            row[bi] = -INFINITY;
        }

        float mg = 1e30f;
#pragma unroll
        for (int p = 0; p < 8; ++p) mg = fminf(mg, vals[p] - vals[p + 1]);
        if (mg < TIE_EPS) {
            int slot = atomicAdd(flags, 1);
            if (slot < cap) flags[2 + slot] = tok;
        }

        float mx = vals[0];
        float g[8], s = 0.f;
#pragma unroll
        for (int p = 0; p < 8; ++p) { g[p] = expf(vals[p] - mx); s += g[p]; }
        float inv = 1.f / s;

        float* rrow = row + 64;
#pragma unroll
        for (int e = 0; e < 64; ++e) rrow[e] = 0.f;
#pragma unroll
        for (int p = 0; p < 8; ++p) rrow[idxs[p]] = g[p] * inv;
#pragma unroll
        for (int e4 = 0; e4 < 16; ++e4) {
            float4 o = make_float4(rrow[e4 * 4], rrow[e4 * 4 + 1],
                                   rrow[e4 * 4 + 2], rrow[e4 * 4 + 3]);
            *(float4*)(out_router + (size_t)tok * E + e4 * 4) = o;
        }
        float4 i0 = make_float4((float)idxs[0], (float)idxs[1], (float)idxs[2], (float)idxs[3]);
        float4 i1 = make_float4((float)idxs[4], (float)idxs[5], (float)idxs[6], (float)idxs[7]);
        *(float4*)(out_idx + (size_t)tok * TOPK)     = i0;
        *(float4*)(out_idx + (size_t)tok * TOPK + 4) = i1;
    }
}

// ---------------- fallback: round-2 full-K router kernel (used when ws too small) --------------
__global__ __launch_bounds__(BLOCK, 2) void router_kernel(
    const float* __restrict__ x, const float* __restrict__ eps,
    const char* __restrict__ wbf,
    const float* __restrict__ b_router, const float* __restrict__ b_noise,
    const float* __restrict__ w_skip, const float* __restrict__ b_skip,
    float* __restrict__ out_router, float* __restrict__ out_idx,
    float* __restrict__ out_skip, int* __restrict__ flags, int cap)
{
    __shared__ __attribute__((aligned(16))) char smem[SMEM_BYTES];
    const int tid = threadIdx.x;
    const int tokBase = blockIdx.x * TM;

    const int lane = tid & 63;
    const int wv   = __builtin_amdgcn_readfirstlane(tid >> 6);
    const int tg   = wv >> 1;
    const int ch   = wv & 1;
    const int q    = lane >> 4;
    const int m    = lane & 15;

    const float* xlane = x + (size_t)(tokBase + tg * 32 + m) * D + q * 8;
    const char*  blane = wbf + (size_t)((q << 7) + (ch << 6) + m) * 16;
    const float* wklane = w_skip + q * 8;

    f32x4 acc[2][4];
#pragma unroll
    for (int tt = 0; tt < 2; ++tt)
#pragma unroll
        for (int cw = 0; cw < 4; ++cw) acc[tt][cw] = (f32x4){0.f, 0.f, 0.f, 0.f};
    float skipAcc[2] = {0.f, 0.f};

    struct Gen {
        float4 a[2][2];
        uint4  b[4][2];
        float4 wk[2];
    };

    auto loadGen = [&](Gen& g, int c) {
        const float* xp = xlane + c * BK;
#pragma unroll
        for (int tt = 0; tt < 2; ++tt) {
            g.a[tt][0] = *(const float4*)(xp + (size_t)tt * 16 * D);
            g.a[tt][1] = *(const float4*)(xp + (size_t)tt * 16 * D + 4);
        }
        const char* bp = blane + (size_t)c * 16384;
#pragma unroll
        for (int cw = 0; cw < 4; ++cw) {
            g.b[cw][0] = *(const uint4*)(bp + cw * 256);
            g.b[cw][1] = *(const uint4*)(bp + cw * 256 + 8192);
        }
        g.wk[0] = *(const float4*)(wklane + c * BK);
        g.wk[1] = *(const float4*)(wklane + c * BK + 4);
    };

    auto computeGen = [&](Gen& g) {
#pragma unroll
        for (int tt = 0; tt < 2; ++tt) {
            float xv[8] = {g.a[tt][0].x, g.a[tt][0].y, g.a[tt][0].z, g.a[tt][0].w,
                           g.a[tt][1].x, g.a[tt][1].y, g.a[tt][1].z, g.a[tt][1].w};
            uint4 hv, lv;
            split_pack8(xv, hv, lv);
            bf16x8 Ah = __builtin_bit_cast(bf16x8, hv);
            bf16x8 Al = __builtin_bit_cast(bf16x8, lv);
#pragma unroll
            for (int cw = 0; cw < 4; ++cw) {
                bf16x8 Bh = __builtin_bit_cast(bf16x8, g.b[cw][0]);
                bf16x8 Bl = __builtin_bit_cast(bf16x8, g.b[cw][1]);
                acc[tt][cw] = __builtin_amdgcn_mfma_f32_16x16x32_bf16(Ah, Bh, acc[tt][cw], 0, 0, 0);
                acc[tt][cw] = __builtin_amdgcn_mfma_f32_16x16x32_bf16(Ah, Bl, acc[tt][cw], 0, 0, 0);
                acc[tt][cw] = __builtin_amdgcn_mfma_f32_16x16x32_bf16(Al, Bh, acc[tt][cw], 0, 0, 0);
            }
            float s = skipAcc[tt];
            s = fmaf(xv[0], g.wk[0].x, s); s = fmaf(xv[1], g.wk[0].y, s);
            s = fmaf(xv[2], g.wk[0].z, s); s = fmaf(xv[3], g.wk[0].w, s);
            s = fmaf(xv[4], g.wk[1].x, s); s = fmaf(xv[5], g.wk[1].y, s);
            s = fmaf(xv[6], g.wk[1].z, s); s = fmaf(xv[7], g.wk[1].w, s);
            skipAcc[tt] = s;
        }
    };

    Gen gA, gB;
    loadGen(gA, 0);
#pragma unroll 1
    for (int c = 0; c < NCHUNK; c += 2) {
        loadGen(gB, c + 1);
        computeGen(gA);
        if (c + 2 < NCHUNK) loadGen(gA, c + 2);
        computeGen(gB);
    }

    float* lg = (float*)smem;
#pragma unroll
    for (int tt = 0; tt < 2; ++tt)
#pragma unroll
        for (int cw = 0; cw < 4; ++cw) {
#pragma unroll
            for (int reg = 0; reg < 4; ++reg) {
                int token = tg * 32 + tt * 16 + q * 4 + reg;
                int col = ch * 64 + cw * 16 + m;
                lg[token * LG_STR + col] = acc[tt][cw][reg];
            }
        }

#pragma unroll
    for (int tt = 0; tt < 2; ++tt) {
        skipAcc[tt] += __shfl_xor(skipAcc[tt], 16);
        skipAcc[tt] += __shfl_xor(skipAcc[tt], 32);
    }
    if (ch == 0 && lane < 16) {
        float* sp = (float*)(smem + SP_OFF);
        sp[tg * 32 + lane]      = skipAcc[0];
        sp[tg * 32 + 16 + lane] = skipAcc[1];
    }
    __syncthreads();

    if (tid < 64) {
        const int t = tid;
        const int tok = tokBase + t;
        float* row = lg + t * LG_STR;

        float sv = ((float*)(smem + SP_OFF))[t] + b_skip[0];
        out_skip[tok] = 1.f / (1.f + expf(-sv));

        const float4* epsr = (const float4*)(eps + (size_t)tok * E);
#pragma unroll 4
        for (int e4 = 0; e4 < 16; ++e4) {
            float4 ep = epsr[e4];
            float epv[4] = {ep.x, ep.y, ep.z, ep.w};
#pragma unroll
            for (int u2 = 0; u2 < 4; ++u2) {
                int e = e4 * 4 + u2;
                float lgv = row[e] + b_router[e];
                float nl  = row[64 + e] + b_noise[e];
                float sp  = fmaxf(nl, 0.f) + log1pf(expf(-fabsf(nl)));
                row[e] = lgv + epv[u2] * sp;
            }
        }

        float vals[9];
        int idxs[8];
        for (int p = 0; p < 9; ++p) {
            float best = -INFINITY;
            int bi = 0;
            for (int e = 0; e < 64; ++e) {
                float v = row[e];
                if (v > best) { best = v; bi = e; }
            }
            vals[p] = best;
            if (p < 8) idxs[p] = bi;
            row[bi] = -INFINITY;
        }

        float mg = 1e30f;
#pragma unroll
        for (int p = 0; p < 8; ++p) mg = fminf(mg, vals[p] - vals[p + 1]);
        if (mg < TIE_EPS) {
            int slot = atomicAdd(flags, 1);
            if (slot < cap) flags[2 + slot] = tok;
        }

        float mx = vals[0];
        float g[8], s = 0.f;
#pragma unroll
        for (int p = 0; p < 8; ++p) { g[p] = expf(vals[p] - mx); s += g[p]; }
        float inv = 1.f / s;

        float* rrow = row + 64;
#pragma unroll
        for (int e = 0; e < 64; ++e) rrow[e] = 0.f;
#pragma unroll
        for (int p = 0; p < 8; ++p) rrow[idxs[p]] = g[p] * inv;
#pragma unroll
        for (int e4 = 0; e4 < 16; ++e4) {
            float4 o = make_float4(rrow[e4 * 4], rrow[e4 * 4 + 1],
                                   rrow[e4 * 4 + 2], rrow[e4 * 4 + 3]);
            *(float4*)(out_router + (size_t)tok * E + e4 * 4) = o;
        }
        float4 i0 = make_float4((float)idxs[0], (float)idxs[1], (float)idxs[2], (float)idxs[3]);
        float4 i1 = make_float4((float)idxs[4], (float)idxs[5], (float)idxs[6], (float)idxs[7]);
        *(float4*)(out_idx + (size_t)tok * TOPK)     = i0;
        *(float4*)(out_idx + (size_t)tok * TOPK + 4) = i1;
    }
}

// ---------------- f64 fixup: one block per token (grid 8192), unroll-4 dot loop ---------------
__global__ __launch_bounds__(256) void fixup_kernel(
    const float* __restrict__ x, const float* __restrict__ eps,
    const float* __restrict__ w_router, const float* __restrict__ b_router,
    const float* __restrict__ w_noise, const float* __restrict__ b_noise,
    float* __restrict__ out_router, float* __restrict__ out_idx,
    const int* __restrict__ flags, int cap)
{
    __shared__ double smR[4][64];
    __shared__ double smN[4][64];
    __shared__ double noisy[64];
    const int tid  = threadIdx.x;
    const int lane = tid & 63;      // expert
    const int qw   = tid >> 6;      // K quarter

    int count = flags[0];
    if (count > cap) count = cap;

    for (int i = blockIdx.x; i < count; i += gridDim.x) {
        int tok = flags[2 + i];
        const float4* xr4 = (const float4*)(x + (size_t)tok * D + qw * 512);
        const float* wrB = w_router + (size_t)(qw * 512) * E + lane;
        const float* wnB = w_noise  + (size_t)(qw * 512) * E + lane;

        double pr0 = 0, pr1 = 0, pr2 = 0, pr3 = 0;
        double pn0 = 0, pn1 = 0, pn2 = 0, pn3 = 0;
#pragma unroll 4
        for (int it = 0; it < 128; ++it) {
            float4 xv = xr4[it];
            const float* wr = wrB + (size_t)(it * 4) * E;
            const float* wn = wnB + (size_t)(it * 4) * E;
            pr0 += (double)xv.x * (double)wr[0];
            pr1 += (double)xv.y * (double)wr[E];
            pr2 += (double)xv.z * (double)wr[2 * E];
            pr3 += (double)xv.w * (double)wr[3 * E];
            pn0 += (double)xv.x * (double)wn[0];
            pn1 += (double)xv.y * (double)wn[E];
            pn2 += (double)xv.z * (double)wn[2 * E];
            pn3 += (double)xv.w * (double)wn[3 * E];
        }
        smR[qw][lane] = (pr0 + pr1) + (pr2 + pr3);
        smN[qw][lane] = (pn0 + pn1) + (pn2 + pn3);
        __syncthreads();

        if (tid < 64) {
            double lgv = smR[0][tid] + smR[1][tid] + smR[2][tid] + smR[3][tid] + (double)b_router[tid];
            double nl  = smN[0][tid] + smN[1][tid] + smN[2][tid] + smN[3][tid] + (double)b_noise[tid];
            double sp  = fmax(nl, 0.0) + log1p(exp(-fabs(nl)));
            noisy[tid] = lgv + (double)eps[(size_t)tok * E + tid] * sp;
        }
        __syncthreads();

        if (tid == 0) {
            double tmp[64];
            for (int j = 0; j < 64; ++j) tmp[j] = noisy[j];
            double vals[8]; int idxs[8];
            for (int p = 0; p < 8; ++p) {
                double best = -1e300; int bi = 0;
                for (int j = 0; j < 64; ++j)
                    if (tmp[j] > best) { best = tmp[j]; bi = j; }
                vals[p] = best; idxs[p] = bi; tmp[bi] = -1e300;
            }
            double mx = vals[0], s = 0.0, g[8];
            for (int p = 0; p < 8; ++p) { g[p] = exp(vals[p] - mx); s += g[p]; }
            float rowv[64];
            for (int j = 0; j < 64; ++j) rowv[j] = 0.f;
            for (int p = 0; p < 8; ++p) rowv[idxs[p]] = (float)(g[p] / s);
            for (int j = 0; j < 64; ++j) out_router[(size_t)tok * E + j] = rowv[j];
            for (int p = 0; p < 8; ++p) out_idx[(size_t)tok * TOPK + p] = (float)idxs[p];
        }
        __syncthreads();
    }
}

extern "C" void kernel_launch(void* const* d_in, const int* in_sizes, int n_in,
                              void* d_out, int out_size, void* d_ws, size_t ws_size,
                              hipStream_t stream) {
    const float* x        = (const float*)d_in[0];
    const float* eps      = (const float*)d_in[1];
    const float* w_router = (const float*)d_in[2];
    const float* b_router = (const float*)d_in[3];
    const float* w_noise  = (const float*)d_in[4];
    const float* b_noise  = (const float*)d_in[5];
    const float* w_skip   = (const float*)d_in[6];
    const float* b_skip   = (const float*)d_in[7];

    float* out = (float*)d_out;
    float* out_router = out;                           // 32768*64
    float* out_idx    = out + (size_t)NTOK * E;        // 32768*8
    float* out_skip   = out_idx + (size_t)NTOK * TOPK; // 32768

    char* wbf  = (char*)d_ws;
    int* flags = (int*)((char*)d_ws + FLAGS_OFF);

    convert_w_kernel<<<dim3(128), dim3(256), 0, stream>>>(w_router, w_noise, wbf);

    if (ws_size >= WS_NEED) {
        int cap = 16384;
        int* pair = (int*)((char*)d_ws + PAIR_OFF);
        hipMemsetAsync((char*)d_ws + FLAGS_OFF, 0, 8, stream);
        hipMemsetAsync((char*)d_ws + PAIR_OFF, 0, NBLK * sizeof(int), stream);

        float* part      = (float*)((char*)d_ws + PART_OFF);
        float* skip_part = (float*)((char*)d_ws + SKIPP_OFF);

        gemm_fused_kernel<<<dim3(2 * NBLK), dim3(BLOCK), 0, stream>>>(
            x, wbf, w_skip, eps, b_router, b_noise, b_skip,
            part, skip_part, out_router, out_idx, out_skip, flags, pair, cap);

        fixup_kernel<<<dim3(8192), dim3(256), 0, stream>>>(
            x, eps, w_router, b_router, w_noise, b_noise,
            out_router, out_idx, flags, cap);
    } else {
        // fallback: verified round-2 single-kernel path
        int cap = 0;
        if (ws_size > WBF_BYTES + 16) {
            size_t c = (ws_size - WBF_BYTES - 8) / 4;
            cap = (c > 16384) ? 16384 : (int)c;
        }
        hipMemsetAsync((char*)d_ws + FLAGS_OFF, 0, 8, stream);

        router_kernel<<<dim3(NBLK), dim3(BLOCK), 0, stream>>>(
            x, eps, wbf, b_router, b_noise, w_skip, b_skip,
            out_router, out_idx, out_skip, flags, cap);

        fixup_kernel<<<dim3(8192), dim3(256), 0, stream>>>(
            x, eps, w_router, b_router, w_noise, b_noise,
            out_router, out_idx, flags, cap);
    }
}

// Round 11
// 544.397 us; speedup vs baseline: 1.3006x; 1.3006x over previous
//
#include <hip/hip_runtime.h>
#include <math.h>

// Problem constants
#define NTOK   32768       // B*S
#define D      2048        // N_EMBED
#define E      64          // NUM_EXPERTS
#define TOPK   8

#define BLOCK  256
#define TM2    32          // tokens per block
#define NBLK2  (NTOK / TM2) // 1024 blocks -> 4 blocks/CU
#define KS     64          // K per stage step (2 MFMA K-chunks)
#define NS     (D / KS)    // 32 steps

// w_bf layout in d_ws: per chunk c (16384 B): hi frags [0,8192), lo frags [8192,16384)
// frag index = koct*128 + col (col 0..63 router, 64..127 noise), 16 B each
#define WBF_BYTES (64 * 16384)       // 1 MiB (64 chunks of BK=32)

// workspace: wbf + flags only (no partials in this structure)
#define FLAGS_OFF   WBF_BYTES        // 8 B counter + tie-token list (<=16384 ints)

// LDS map (bytes): A double-buffer [0,16384): buf b hi at b*8192, lo at b*8192+4096.
// wsk float[2048] at 16384. sps float[32] at 24576. Epilogue lg float[32][133]=17024 B
// reuses [0,17024) (A bufs + head of wsk -- both dead after the K loop).
#define A_HI(b)   ((b) * 8192)
#define A_LO(b)   ((b) * 8192 + 4096)
#define WSK2_OFF  16384
#define SPS2_OFF  24576
#define SMEM2     24704
#define LG_STR    133

// r8 verified: 3e-4 band -> fixup ~700 tokens, out of top-5, absmax 0.0156 (passes).
#define TIE_EPS 3e-4f

typedef __bf16 bf16x8 __attribute__((ext_vector_type(8)));
typedef __bf16 bf16x2 __attribute__((ext_vector_type(2)));
typedef float  f32x4  __attribute__((ext_vector_type(4)));

__device__ __forceinline__ unsigned short f2bf_rne(float f) {
    unsigned int u = __float_as_uint(f);
    u += 0x7FFFu + ((u >> 16) & 1u);
    return (unsigned short)(u >> 16);
}

// v1: manual bit-twiddle pack (convert_w, verified)
__device__ __forceinline__ void split_pack8(const float* xv, uint4& hv, uint4& lv) {
    unsigned int h[8], l[8];
#pragma unroll
    for (int j = 0; j < 8; ++j) {
        unsigned short hb = f2bf_rne(xv[j]);
        float hf = __uint_as_float(((unsigned int)hb) << 16);
        unsigned short lb = f2bf_rne(xv[j] - hf);
        h[j] = hb; l[j] = lb;
    }
    hv.x = h[0] | (h[1] << 16); hv.y = h[2] | (h[3] << 16);
    hv.z = h[4] | (h[5] << 16); hv.w = h[6] | (h[7] << 16);
    lv.x = l[0] | (l[1] << 16); lv.y = l[2] | (l[3] << 16);
    lv.z = l[4] | (l[5] << 16); lv.w = l[6] | (l[7] << 16);
}

// v2: native casts -> v_cvt_pk_bf16_f32 (RNE, bit-identical to v1; verified r4-r8)
__device__ __forceinline__ unsigned int pk2(float a, float b) {
    bf16x2 p;
    p[0] = (__bf16)a; p[1] = (__bf16)b;
    return __builtin_bit_cast(unsigned int, p);
}
__device__ __forceinline__ void split_pack8_v2(const float* xv, uint4& hv, uint4& lv) {
    unsigned int h[4], l[4];
#pragma unroll
    for (int p = 0; p < 4; ++p) {
        float a = xv[2 * p], b = xv[2 * p + 1];
        unsigned int hu = pk2(a, b);
        float fa = __uint_as_float(hu << 16);
        float fb = __uint_as_float(hu & 0xFFFF0000u);
        h[p] = hu;
        l[p] = pk2(a - fa, b - fb);
    }
    hv.x = h[0]; hv.y = h[1]; hv.z = h[2]; hv.w = h[3];
    lv.x = l[0]; lv.y = l[1]; lv.z = l[2]; lv.w = l[3];
}

// ---------------- pre-kernel: convert W (router||noise) to split-bf16 fragment layout ----------
__global__ __launch_bounds__(256) void convert_w_kernel(
    const float* __restrict__ wr, const float* __restrict__ wn, char* __restrict__ wbf)
{
    int u = blockIdx.x * 256 + threadIdx.x;
    int col  = u & 127;
    int koct = (u >> 7) & 3;
    int c    = u >> 9;
    const float* src = (col < 64)
        ? (wr + (size_t)(c * 32 + koct * 8) * E + col)
        : (wn + (size_t)(c * 32 + koct * 8) * E + (col - 64));
    float xv[8];
#pragma unroll
    for (int j = 0; j < 8; ++j) xv[j] = src[(size_t)j * E];
    uint4 hv, lv;
    split_pack8(xv, hv, lv);
    char* dst = wbf + (size_t)c * 16384 + (size_t)(koct * 128 + col) * 16;
    *(uint4*)dst = hv;
    *(uint4*)(dst + 8192) = lv;
}

// ---------------- router32: TM=32 full-K, A LDS-staged (coalesced), B reg-direct ---------------
// grid 1024 (4 blocks/CU). 4 waves: wave wv owns cols wv*32..wv*32+31, ALL 32 tokens.
// A is staged once per block per K-step (each token row loaded as 256B contiguous by 8 threads,
// packed to split-bf16, XOR-swizzled into LDS); all 4 waves read the same 8KB fragments.
// B (1 MiB, L2-resident) is loaded per-lane register-direct (r2-verified pattern).
// One barrier per 64-K step (32 total). Epilogue fused (r1/r8-verified math), no combine pass.
__global__ __launch_bounds__(BLOCK) void router32_kernel(
    const float* __restrict__ x, const char* __restrict__ wbf,
    const float* __restrict__ w_skip, const float* __restrict__ eps,
    const float* __restrict__ b_router, const float* __restrict__ b_noise,
    const float* __restrict__ b_skip,
    float* __restrict__ out_router, float* __restrict__ out_idx,
    float* __restrict__ out_skip, int* __restrict__ flags, int cap)
{
    __shared__ __attribute__((aligned(16))) char smem[SMEM2];
    const int tid = threadIdx.x;
    const int tokBase = blockIdx.x * TM2;

    const int lane = tid & 63;
    const int wv   = __builtin_amdgcn_readfirstlane(tid >> 6);  // col quarter 0..3
    const int q    = lane >> 4;      // k-octet within 32-K chunk
    const int m    = lane & 15;

    // staging mapping: 8 threads per token, 256B contiguous per token row per step
    const int tokS = tid >> 3;       // 0..31
    const int k8S  = tid & 7;        // 0..7 (k-octet within 64-K step)
    const float* xstage = x + (size_t)(tokBase + tokS) * D + k8S * 8;
    float* wsk = (float*)(smem + WSK2_OFF);

    // B per-lane base: frag idx q*128 + (wv*32 + cw*16 + m), 16B each; cw adds 256B
    const char* blane = wbf + (size_t)((q << 7) + (wv << 5) + m) * 16;

    f32x4 acc[2][2];
#pragma unroll
    for (int tt = 0; tt < 2; ++tt)
#pragma unroll
        for (int cw = 0; cw < 2; ++cw) acc[tt][cw] = (f32x4){0.f, 0.f, 0.f, 0.f};
    float skipAcc = 0.f;

    // A store: slot = k8*32 + (token ^ k8). Store side: quarter-wave = 2 tokens x 8 k8 ->
    // bank residues t3^k8 cover 0..7 twice -> 2-way (free, m136). Read side: 16 lanes fixed
    // K8 read 16 XOR-permuted consecutive cells -> 2-way.
    auto storeA = [&](int buf, float4 a0, float4 a1) {
        float xv[8] = {a0.x, a0.y, a0.z, a0.w, a1.x, a1.y, a1.z, a1.w};
        uint4 hv, lv;
        split_pack8_v2(xv, hv, lv);
        int slot = (k8S << 5) + (tokS ^ k8S);
        *(uint4*)(smem + A_HI(buf) + slot * 16) = hv;
        *(uint4*)(smem + A_LO(buf) + slot * 16) = lv;
    };

    auto skipFma = [&](float4 a0, float4 a1, int s) {
        const float* wk = wsk + s * KS + k8S * 8;
        skipAcc = fmaf(a0.x, wk[0], skipAcc); skipAcc = fmaf(a0.y, wk[1], skipAcc);
        skipAcc = fmaf(a0.z, wk[2], skipAcc); skipAcc = fmaf(a0.w, wk[3], skipAcc);
        skipAcc = fmaf(a1.x, wk[4], skipAcc); skipAcc = fmaf(a1.y, wk[5], skipAcc);
        skipAcc = fmaf(a1.z, wk[6], skipAcc); skipAcc = fmaf(a1.w, wk[7], skipAcc);
    };

    auto compute = [&](int buf, int s) {
#pragma unroll
        for (int kk = 0; kk < 2; ++kk) {            // MFMA chunk within the 64-K step
            const int K8 = kk * 4 + q;              // k-octet 0..7
            uint4 ah[2], al[2], bh[2], bl[2];
#pragma unroll
            for (int tt = 0; tt < 2; ++tt) {
                int slot = (K8 << 5) + ((tt * 16 + m) ^ K8);
                ah[tt] = *(const uint4*)(smem + A_HI(buf) + slot * 16);
                al[tt] = *(const uint4*)(smem + A_LO(buf) + slot * 16);
            }
            const char* bp = blane + (size_t)(2 * s + kk) * 16384;
#pragma unroll
            for (int cw = 0; cw < 2; ++cw) {
                bh[cw] = *(const uint4*)(bp + cw * 256);
                bl[cw] = *(const uint4*)(bp + cw * 256 + 8192);
            }
#pragma unroll
            for (int tt = 0; tt < 2; ++tt) {
                bf16x8 Ah = __builtin_bit_cast(bf16x8, ah[tt]);
                bf16x8 Al = __builtin_bit_cast(bf16x8, al[tt]);
#pragma unroll
                for (int cw = 0; cw < 2; ++cw) {
                    bf16x8 Bh = __builtin_bit_cast(bf16x8, bh[cw]);
                    bf16x8 Bl = __builtin_bit_cast(bf16x8, bl[cw]);
                    acc[tt][cw] = __builtin_amdgcn_mfma_f32_16x16x32_bf16(Ah, Bh, acc[tt][cw], 0, 0, 0);
                    acc[tt][cw] = __builtin_amdgcn_mfma_f32_16x16x32_bf16(Ah, Bl, acc[tt][cw], 0, 0, 0);
                    acc[tt][cw] = __builtin_amdgcn_mfma_f32_16x16x32_bf16(Al, Bh, acc[tt][cw], 0, 0, 0);
                }
            }
        }
    };

    // ---- prologue: stage w_skip, then step-0 A tile ----
    ((float4*)wsk)[tid]       = ((const float4*)w_skip)[tid];
    ((float4*)wsk)[tid + 256] = ((const float4*)w_skip)[tid + 256];
    float4 ra0 = *(const float4*)(xstage);
    float4 ra1 = *(const float4*)(xstage + 4);
    __syncthreads();                 // wsk visible (skipFma uses it)
    storeA(0, ra0, ra1);
    skipFma(ra0, ra1, 0);
    __syncthreads();                 // buf0 visible

    // ---- K loop: 32 steps, LDS double-buffer, ONE barrier per step ----
#pragma unroll 1
    for (int s = 0; s < NS; ++s) {
        int cur = s & 1;
        float4 rb0, rb1;
        if (s + 1 < NS) {
            rb0 = *(const float4*)(xstage + (s + 1) * KS);
            rb1 = *(const float4*)(xstage + (s + 1) * KS + 4);
        }
        compute(cur, s);
        if (s + 1 < NS) {
            storeA(cur ^ 1, rb0, rb1);   // safe: cur^1 last read at step s-1, barrier between
            skipFma(rb0, rb1, s + 1);
        }
        __syncthreads();
    }

    // ---- dump accumulators to logits[32][133] (C/D: col=lane&15, row=q*4+reg) ----
    float* lg = (float*)smem;        // reuses A bufs + wsk head (dead)
#pragma unroll
    for (int tt = 0; tt < 2; ++tt)
#pragma unroll
        for (int cw = 0; cw < 2; ++cw)
#pragma unroll
            for (int reg = 0; reg < 4; ++reg) {
                int token = tt * 16 + q * 4 + reg;
                int col = wv * 32 + cw * 16 + m;
                lg[token * LG_STR + col] = acc[tt][cw][reg];
            }

    // skip reduce across the 8 k8 lanes of each token (lanes differ in bits 0..2)
    skipAcc += __shfl_xor(skipAcc, 1);
    skipAcc += __shfl_xor(skipAcc, 2);
    skipAcc += __shfl_xor(skipAcc, 4);
    if (k8S == 0) ((float*)(smem + SPS2_OFF))[tokS] = skipAcc;
    __syncthreads();

    // ---- epilogue: one lane per token (identical math to verified r8 combine) ----
    if (tid < TM2) {
        const int t = tid;
        const int tok = tokBase + t;
        float* row = lg + t * LG_STR;

        float sv = ((float*)(smem + SPS2_OFF))[t] + b_skip[0];
        out_skip[tok] = 1.f / (1.f + expf(-sv));

        const float4* epsr = (const float4*)(eps + (size_t)tok * E);
#pragma unroll 4
        for (int e4 = 0; e4 < 16; ++e4) {
            float4 ep = epsr[e4];
            float epv[4] = {ep.x, ep.y, ep.z, ep.w};
#pragma unroll
            for (int u2 = 0; u2 < 4; ++u2) {
                int e = e4 * 4 + u2;
                float lgv = row[e] + b_router[e];
                float nl  = row[64 + e] + b_noise[e];
                float sp  = fmaxf(nl, 0.f) + log1pf(expf(-fabsf(nl)));
                row[e] = lgv + epv[u2] * sp;
            }
        }

        // top-9 (strict '>' => lowest index wins ties; matches lax.top_k)
        float vals[9];
        int idxs[8];
        for (int p = 0; p < 9; ++p) {
            float best = -INFINITY;
            int bi = 0;
            for (int e = 0; e < 64; ++e) {
                float v = row[e];
                if (v > best) { best = v; bi = e; }
            }
            vals[p] = best;
            if (p < 8) idxs[p] = bi;
            row[bi] = -INFINITY;
        }

        float mg = 1e30f;
#pragma unroll
        for (int p = 0; p < 8; ++p) mg = fminf(mg, vals[p] - vals[p + 1]);
        if (mg < TIE_EPS) {
            int slot = atomicAdd(flags, 1);
            if (slot < cap) flags[2 + slot] = tok;
        }

        float mx = vals[0];
        float g[8], s = 0.f;
#pragma unroll
        for (int p = 0; p < 8; ++p) { g[p] = expf(vals[p] - mx); s += g[p]; }
        float inv = 1.f / s;

        float* rrow = row + 64;
#pragma unroll
        for (int e = 0; e < 64; ++e) rrow[e] = 0.f;
#pragma unroll
        for (int p = 0; p < 8; ++p) rrow[idxs[p]] = g[p] * inv;
#pragma unroll
        for (int e4 = 0; e4 < 16; ++e4) {
            float4 o = make_float4(rrow[e4 * 4], rrow[e4 * 4 + 1],
                                   rrow[e4 * 4 + 2], rrow[e4 * 4 + 3]);
            *(float4*)(out_router + (size_t)tok * E + e4 * 4) = o;
        }
        float4 i0 = make_float4((float)idxs[0], (float)idxs[1], (float)idxs[2], (float)idxs[3]);
        float4 i1 = make_float4((float)idxs[4], (float)idxs[5], (float)idxs[6], (float)idxs[7]);
        *(float4*)(out_idx + (size_t)tok * TOPK)     = i0;
        *(float4*)(out_idx + (size_t)tok * TOPK + 4) = i1;
    }
}

// ---------------- f64 fixup: one block per token (grid 8192), unroll-4 dot loop ---------------
__global__ __launch_bounds__(256) void fixup_kernel(
    const float* __restrict__ x, const float* __restrict__ eps,
    const float* __restrict__ w_router, const float* __restrict__ b_router,
    const float* __restrict__ w_noise, const float* __restrict__ b_noise,
    float* __restrict__ out_router, float* __restrict__ out_idx,
    const int* __restrict__ flags, int cap)
{
    __shared__ double smR[4][64];
    __shared__ double smN[4][64];
    __shared__ double noisy[64];
    const int tid  = threadIdx.x;
    const int lane = tid & 63;      // expert
    const int qw   = tid >> 6;      // K quarter

    int count = flags[0];
    if (count > cap) count = cap;

    for (int i = blockIdx.x; i < count; i += gridDim.x) {
        int tok = flags[2 + i];
        const float4* xr4 = (const float4*)(x + (size_t)tok * D + qw * 512);
        const float* wrB = w_router + (size_t)(qw * 512) * E + lane;
        const float* wnB = w_noise  + (size_t)(qw * 512) * E + lane;

        double pr0 = 0, pr1 = 0, pr2 = 0, pr3 = 0;
        double pn0 = 0, pn1 = 0, pn2 = 0, pn3 = 0;
#pragma unroll 4
        for (int it = 0; it < 128; ++it) {
            float4 xv = xr4[it];
            const float* wr = wrB + (size_t)(it * 4) * E;
            const float* wn = wnB + (size_t)(it * 4) * E;
            pr0 += (double)xv.x * (double)wr[0];
            pr1 += (double)xv.y * (double)wr[E];
            pr2 += (double)xv.z * (double)wr[2 * E];
            pr3 += (double)xv.w * (double)wr[3 * E];
            pn0 += (double)xv.x * (double)wn[0];
            pn1 += (double)xv.y * (double)wn[E];
            pn2 += (double)xv.z * (double)wn[2 * E];
            pn3 += (double)xv.w * (double)wn[3 * E];
        }
        smR[qw][lane] = (pr0 + pr1) + (pr2 + pr3);
        smN[qw][lane] = (pn0 + pn1) + (pn2 + pn3);
        __syncthreads();

        if (tid < 64) {
            double lgv = smR[0][tid] + smR[1][tid] + smR[2][tid] + smR[3][tid] + (double)b_router[tid];
            double nl  = smN[0][tid] + smN[1][tid] + smN[2][tid] + smN[3][tid] + (double)b_noise[tid];
            double sp  = fmax(nl, 0.0) + log1p(exp(-fabs(nl)));
            noisy[tid] = lgv + (double)eps[(size_t)tok * E + tid] * sp;
        }
        __syncthreads();

        if (tid == 0) {
            double tmp[64];
            for (int j = 0; j < 64; ++j) tmp[j] = noisy[j];
            double vals[8]; int idxs[8];
            for (int p = 0; p < 8; ++p) {
                double best = -1e300; int bi = 0;
                for (int j = 0; j < 64; ++j)
                    if (tmp[j] > best) { best = tmp[j]; bi = j; }
                vals[p] = best; idxs[p] = bi; tmp[bi] = -1e300;
            }
            double mx = vals[0], s = 0.0, g[8];
            for (int p = 0; p < 8; ++p) { g[p] = exp(vals[p] - mx); s += g[p]; }
            float rowv[64];
            for (int j = 0; j < 64; ++j) rowv[j] = 0.f;
            for (int p = 0; p < 8; ++p) rowv[idxs[p]] = (float)(g[p] / s);
            for (int j = 0; j < 64; ++j) out_router[(size_t)tok * E + j] = rowv[j];
            for (int p = 0; p < 8; ++p) out_idx[(size_t)tok * TOPK + p] = (float)idxs[p];
        }
        __syncthreads();
    }
}

extern "C" void kernel_launch(void* const* d_in, const int* in_sizes, int n_in,
                              void* d_out, int out_size, void* d_ws, size_t ws_size,
                              hipStream_t stream) {
    const float* x        = (const float*)d_in[0];
    const float* eps      = (const float*)d_in[1];
    const float* w_router = (const float*)d_in[2];
    const float* b_router = (const float*)d_in[3];
    const float* w_noise  = (const float*)d_in[4];
    const float* b_noise  = (const float*)d_in[5];
    const float* w_skip   = (const float*)d_in[6];
    const float* b_skip   = (const float*)d_in[7];

    float* out = (float*)d_out;
    float* out_router = out;                           // 32768*64
    float* out_idx    = out + (size_t)NTOK * E;        // 32768*8
    float* out_skip   = out_idx + (size_t)NTOK * TOPK; // 32768

    char* wbf  = (char*)d_ws;
    int* flags = (int*)((char*)d_ws + FLAGS_OFF);

    int cap = 0;
    if (ws_size > FLAGS_OFF + 16) {
        size_t c = (ws_size - FLAGS_OFF - 8) / 4;
        cap = (c > 16384) ? 16384 : (int)c;
    }

    convert_w_kernel<<<dim3(128), dim3(256), 0, stream>>>(w_router, w_noise, wbf);
    hipMemsetAsync((char*)d_ws + FLAGS_OFF, 0, 8, stream);

    router32_kernel<<<dim3(NBLK2), dim3(BLOCK), 0, stream>>>(
        x, wbf, w_skip, eps, b_router, b_noise, b_skip,
        out_router, out_idx, out_skip, flags, cap);

    fixup_kernel<<<dim3(8192), dim3(256), 0, stream>>>(
        x, eps, w_router, b_router, w_noise, b_noise,
        out_router, out_idx, flags, cap);
}

// Round 12
// 517.976 us; speedup vs baseline: 1.3669x; 1.0510x over previous
//
#include <hip/hip_runtime.h>
#include <math.h>

// Problem constants
#define NTOK   32768       // B*S
#define D      2048        // N_EMBED
#define E      64          // NUM_EXPERTS
#define TOPK   8

#define BLOCK  256
#define TM2    32           // tokens per block
#define NBLK2  (NTOK / TM2) // 1024 blocks -> 4 blocks/CU
#define KS     128          // K per stage step (4 MFMA K-chunks)  [r11: 64]
#define NS     (D / KS)     // 16 steps -> 16 barrier chains (r11: 32)

// w_bf layout in d_ws: per chunk c (16384 B): hi frags [0,8192), lo frags [8192,16384)
// frag index = koct*128 + col (col 0..63 router, 64..127 noise), 16 B each
#define WBF_BYTES (64 * 16384)       // 1 MiB (64 chunks of BK=32)

// workspace: wbf + flags only
#define FLAGS_OFF   WBF_BYTES        // 8 B counter + tie-token list (<=16384 ints)

// LDS map (bytes): A double-buffer [0,32768): buf b hi at b*16384, lo at +8192.
// Slot = K8*32 + (token ^ K8), K8 = 0..15, 16 B each -> 8 KB hi per buf.
// sps float[32] at 32768. Epilogue lg float[32][133] = 17024 B reuses [0,17024).
// w_skip is NOT LDS-staged (8 KB, L2-hot, read per-lane) to keep 4 blocks/CU.
#define A_HI(b)   ((b) * 16384)
#define A_LO(b)   ((b) * 16384 + 8192)
#define SPS2_OFF  32768
#define SMEM2     32896
#define LG_STR    133

// r8 verified: 3e-4 band -> fixup ~700 tokens, absmax 0.0156 (passes).
#define TIE_EPS 3e-4f

typedef __bf16 bf16x8 __attribute__((ext_vector_type(8)));
typedef __bf16 bf16x2 __attribute__((ext_vector_type(2)));
typedef float  f32x4  __attribute__((ext_vector_type(4)));

__device__ __forceinline__ unsigned short f2bf_rne(float f) {
    unsigned int u = __float_as_uint(f);
    u += 0x7FFFu + ((u >> 16) & 1u);
    return (unsigned short)(u >> 16);
}

// v1: manual bit-twiddle pack (convert_w, verified)
__device__ __forceinline__ void split_pack8(const float* xv, uint4& hv, uint4& lv) {
    unsigned int h[8], l[8];
#pragma unroll
    for (int j = 0; j < 8; ++j) {
        unsigned short hb = f2bf_rne(xv[j]);
        float hf = __uint_as_float(((unsigned int)hb) << 16);
        unsigned short lb = f2bf_rne(xv[j] - hf);
        h[j] = hb; l[j] = lb;
    }
    hv.x = h[0] | (h[1] << 16); hv.y = h[2] | (h[3] << 16);
    hv.z = h[4] | (h[5] << 16); hv.w = h[6] | (h[7] << 16);
    lv.x = l[0] | (l[1] << 16); lv.y = l[2] | (l[3] << 16);
    lv.z = l[4] | (l[5] << 16); lv.w = l[6] | (l[7] << 16);
}

// v2: native casts -> v_cvt_pk_bf16_f32 (RNE, bit-identical to v1; verified r4-r11)
__device__ __forceinline__ unsigned int pk2(float a, float b) {
    bf16x2 p;
    p[0] = (__bf16)a; p[1] = (__bf16)b;
    return __builtin_bit_cast(unsigned int, p);
}
__device__ __forceinline__ void split_pack8_v2(const float* xv, uint4& hv, uint4& lv) {
    unsigned int h[4], l[4];
#pragma unroll
    for (int p = 0; p < 4; ++p) {
        float a = xv[2 * p], b = xv[2 * p + 1];
        unsigned int hu = pk2(a, b);
        float fa = __uint_as_float(hu << 16);
        float fb = __uint_as_float(hu & 0xFFFF0000u);
        h[p] = hu;
        l[p] = pk2(a - fa, b - fb);
    }
    hv.x = h[0]; hv.y = h[1]; hv.z = h[2]; hv.w = h[3];
    lv.x = l[0]; lv.y = l[1]; lv.z = l[2]; lv.w = l[3];
}

// ---------------- pre-kernel: convert W (router||noise) to split-bf16 fragment layout ----------
__global__ __launch_bounds__(256) void convert_w_kernel(
    const float* __restrict__ wr, const float* __restrict__ wn, char* __restrict__ wbf)
{
    int u = blockIdx.x * 256 + threadIdx.x;
    int col  = u & 127;
    int koct = (u >> 7) & 3;
    int c    = u >> 9;
    const float* src = (col < 64)
        ? (wr + (size_t)(c * 32 + koct * 8) * E + col)
        : (wn + (size_t)(c * 32 + koct * 8) * E + (col - 64));
    float xv[8];
#pragma unroll
    for (int j = 0; j < 8; ++j) xv[j] = src[(size_t)j * E];
    uint4 hv, lv;
    split_pack8(xv, hv, lv);
    char* dst = wbf + (size_t)c * 16384 + (size_t)(koct * 128 + col) * 16;
    *(uint4*)dst = hv;
    *(uint4*)(dst + 8192) = lv;
}

// ---------------- router32: TM=32 full-K, KS=128 (16 barrier chains), A LDS-staged -------------
// r11 falsified occupancy theory (occ 20->40%, dur unchanged 166): each block is bound by a
// serial per-step chain (barrier -> B L2 latency -> MFMA -> vmcnt(0) drain of x prefetch).
// This round halves the NUMBER of chains: KS 64->128, 32->16 steps, 2x MFMA per drain.
// Per-thread staging: token = tid>>3, octets o and o+8 (4 float4 loads = 512B/token by 8 thr).
__global__ __launch_bounds__(BLOCK) void router32_kernel(
    const float* __restrict__ x, const char* __restrict__ wbf,
    const float* __restrict__ w_skip, const float* __restrict__ eps,
    const float* __restrict__ b_router, const float* __restrict__ b_noise,
    const float* __restrict__ b_skip,
    float* __restrict__ out_router, float* __restrict__ out_idx,
    float* __restrict__ out_skip, int* __restrict__ flags, int cap)
{
    __shared__ __attribute__((aligned(16))) char smem[SMEM2];
    const int tid = threadIdx.x;
    const int tokBase = blockIdx.x * TM2;

    const int lane = tid & 63;
    const int wv   = __builtin_amdgcn_readfirstlane(tid >> 6);  // col quarter 0..3
    const int q    = lane >> 4;      // k-octet within 32-K chunk
    const int m    = lane & 15;

    // staging mapping: 8 threads per token; thread covers octets o1 and o1+8 of the 128-K step
    const int tokS = tid >> 3;       // 0..31
    const int o1   = tid & 7;        // 0..7
    const int o2   = o1 + 8;         // 8..15
    const float* xrow = x + (size_t)(tokBase + tokS) * D;

    // B per-lane base: frag idx q*128 + (wv*32 + cw*16 + m), 16B each; cw adds 256B
    const char* blane = wbf + (size_t)((q << 7) + (wv << 5) + m) * 16;

    f32x4 acc[2][2];
#pragma unroll
    for (int tt = 0; tt < 2; ++tt)
#pragma unroll
        for (int cw = 0; cw < 2; ++cw) acc[tt][cw] = (f32x4){0.f, 0.f, 0.f, 0.f};
    float skipAcc = 0.f;

    // A store slot = K8*32 + (token ^ K8): store side 2-way, read side 2-way (free, m136)
    auto storeOct = [&](int buf, int o, float4 a0, float4 a1) {
        float xv[8] = {a0.x, a0.y, a0.z, a0.w, a1.x, a1.y, a1.z, a1.w};
        uint4 hv, lv;
        split_pack8_v2(xv, hv, lv);
        int slot = (o << 5) + (tokS ^ o);
        *(uint4*)(smem + A_HI(buf) + slot * 16) = hv;
        *(uint4*)(smem + A_LO(buf) + slot * 16) = lv;
    };

    auto skipOct = [&](float4 a0, float4 a1, int s, int o) {
        const float* wk = w_skip + s * KS + o * 8;   // global, L2/L1-hot (8 KB total)
        skipAcc = fmaf(a0.x, wk[0], skipAcc); skipAcc = fmaf(a0.y, wk[1], skipAcc);
        skipAcc = fmaf(a0.z, wk[2], skipAcc); skipAcc = fmaf(a0.w, wk[3], skipAcc);
        skipAcc = fmaf(a1.x, wk[4], skipAcc); skipAcc = fmaf(a1.y, wk[5], skipAcc);
        skipAcc = fmaf(a1.z, wk[6], skipAcc); skipAcc = fmaf(a1.w, wk[7], skipAcc);
    };

    auto compute = [&](int buf, int s) {
#pragma unroll
        for (int kk = 0; kk < 4; ++kk) {            // 32-K MFMA chunk within the 128-K step
            const int K8 = kk * 4 + q;              // k-octet 0..15
            uint4 ah[2], al[2], bh[2], bl[2];
#pragma unroll
            for (int tt = 0; tt < 2; ++tt) {
                int slot = (K8 << 5) + ((tt * 16 + m) ^ K8);
                ah[tt] = *(const uint4*)(smem + A_HI(buf) + slot * 16);
                al[tt] = *(const uint4*)(smem + A_LO(buf) + slot * 16);
            }
            const char* bp = blane + (size_t)(4 * s + kk) * 16384;   // chunk c = 4s+kk (0..63)
#pragma unroll
            for (int cw = 0; cw < 2; ++cw) {
                bh[cw] = *(const uint4*)(bp + cw * 256);
                bl[cw] = *(const uint4*)(bp + cw * 256 + 8192);
            }
#pragma unroll
            for (int tt = 0; tt < 2; ++tt) {
                bf16x8 Ah = __builtin_bit_cast(bf16x8, ah[tt]);
                bf16x8 Al = __builtin_bit_cast(bf16x8, al[tt]);
#pragma unroll
                for (int cw = 0; cw < 2; ++cw) {
                    bf16x8 Bh = __builtin_bit_cast(bf16x8, bh[cw]);
                    bf16x8 Bl = __builtin_bit_cast(bf16x8, bl[cw]);
                    acc[tt][cw] = __builtin_amdgcn_mfma_f32_16x16x32_bf16(Ah, Bh, acc[tt][cw], 0, 0, 0);
                    acc[tt][cw] = __builtin_amdgcn_mfma_f32_16x16x32_bf16(Ah, Bl, acc[tt][cw], 0, 0, 0);
                    acc[tt][cw] = __builtin_amdgcn_mfma_f32_16x16x32_bf16(Al, Bh, acc[tt][cw], 0, 0, 0);
                }
            }
        }
    };

    // ---- prologue: stage step-0 A tile ----
    {
        float4 p0 = *(const float4*)(xrow + o1 * 8);
        float4 p1 = *(const float4*)(xrow + o1 * 8 + 4);
        float4 p2 = *(const float4*)(xrow + o2 * 8);
        float4 p3 = *(const float4*)(xrow + o2 * 8 + 4);
        storeOct(0, o1, p0, p1);
        storeOct(0, o2, p2, p3);
        skipOct(p0, p1, 0, o1);
        skipOct(p2, p3, 0, o2);
    }
    __syncthreads();

    // ---- K loop: 16 steps, LDS double-buffer, ONE barrier per step ----
#pragma unroll 1
    for (int s = 0; s < NS; ++s) {
        int cur = s & 1;
        float4 rb0, rb1, rb2, rb3;
        if (s + 1 < NS) {
            const float* xp = xrow + (s + 1) * KS;
            rb0 = *(const float4*)(xp + o1 * 8);
            rb1 = *(const float4*)(xp + o1 * 8 + 4);
            rb2 = *(const float4*)(xp + o2 * 8);
            rb3 = *(const float4*)(xp + o2 * 8 + 4);
        }
        compute(cur, s);
        if (s + 1 < NS) {
            storeOct(cur ^ 1, o1, rb0, rb1);   // safe: cur^1 last read at step s-1, barrier between
            storeOct(cur ^ 1, o2, rb2, rb3);
            skipOct(rb0, rb1, s + 1, o1);
            skipOct(rb2, rb3, s + 1, o2);
        }
        __syncthreads();
    }

    // ---- dump accumulators to logits[32][133] (C/D: col=lane&15, row=q*4+reg) ----
    float* lg = (float*)smem;        // reuses A bufs (dead)
#pragma unroll
    for (int tt = 0; tt < 2; ++tt)
#pragma unroll
        for (int cw = 0; cw < 2; ++cw)
#pragma unroll
            for (int reg = 0; reg < 4; ++reg) {
                int token = tt * 16 + q * 4 + reg;
                int col = wv * 32 + cw * 16 + m;
                lg[token * LG_STR + col] = acc[tt][cw][reg];
            }

    // skip reduce across the 8 staging lanes of each token (lanes differ in bits 0..2)
    skipAcc += __shfl_xor(skipAcc, 1);
    skipAcc += __shfl_xor(skipAcc, 2);
    skipAcc += __shfl_xor(skipAcc, 4);
    if (o1 == 0) ((float*)(smem + SPS2_OFF))[tokS] = skipAcc;
    __syncthreads();

    // ---- epilogue: one lane per token (identical math to verified r8/r11) ----
    if (tid < TM2) {
        const int t = tid;
        const int tok = tokBase + t;
        float* row = lg + t * LG_STR;

        float sv = ((float*)(smem + SPS2_OFF))[t] + b_skip[0];
        out_skip[tok] = 1.f / (1.f + expf(-sv));

        const float4* epsr = (const float4*)(eps + (size_t)tok * E);
#pragma unroll 4
        for (int e4 = 0; e4 < 16; ++e4) {
            float4 ep = epsr[e4];
            float epv[4] = {ep.x, ep.y, ep.z, ep.w};
#pragma unroll
            for (int u2 = 0; u2 < 4; ++u2) {
                int e = e4 * 4 + u2;
                float lgv = row[e] + b_router[e];
                float nl  = row[64 + e] + b_noise[e];
                float sp  = fmaxf(nl, 0.f) + log1pf(expf(-fabsf(nl)));
                row[e] = lgv + epv[u2] * sp;
            }
        }

        // top-9 (strict '>' => lowest index wins ties; matches lax.top_k)
        float vals[9];
        int idxs[8];
        for (int p = 0; p < 9; ++p) {
            float best = -INFINITY;
            int bi = 0;
            for (int e = 0; e < 64; ++e) {
                float v = row[e];
                if (v > best) { best = v; bi = e; }
            }
            vals[p] = best;
            if (p < 8) idxs[p] = bi;
            row[bi] = -INFINITY;
        }

        float mg = 1e30f;
#pragma unroll
        for (int p = 0; p < 8; ++p) mg = fminf(mg, vals[p] - vals[p + 1]);
        if (mg < TIE_EPS) {
            int slot = atomicAdd(flags, 1);
            if (slot < cap) flags[2 + slot] = tok;
        }

        float mx = vals[0];
        float g[8], s = 0.f;
#pragma unroll
        for (int p = 0; p < 8; ++p) { g[p] = expf(vals[p] - mx); s += g[p]; }
        float inv = 1.f / s;

        float* rrow = row + 64;
#pragma unroll
        for (int e = 0; e < 64; ++e) rrow[e] = 0.f;
#pragma unroll
        for (int p = 0; p < 8; ++p) rrow[idxs[p]] = g[p] * inv;
#pragma unroll
        for (int e4 = 0; e4 < 16; ++e4) {
            float4 o = make_float4(rrow[e4 * 4], rrow[e4 * 4 + 1],
                                   rrow[e4 * 4 + 2], rrow[e4 * 4 + 3]);
            *(float4*)(out_router + (size_t)tok * E + e4 * 4) = o;
        }
        float4 i0 = make_float4((float)idxs[0], (float)idxs[1], (float)idxs[2], (float)idxs[3]);
        float4 i1 = make_float4((float)idxs[4], (float)idxs[5], (float)idxs[6], (float)idxs[7]);
        *(float4*)(out_idx + (size_t)tok * TOPK)     = i0;
        *(float4*)(out_idx + (size_t)tok * TOPK + 4) = i1;
    }
}

// ---------------- f64 fixup: one block per token (grid 8192), unroll-4 dot loop ---------------
__global__ __launch_bounds__(256) void fixup_kernel(
    const float* __restrict__ x, const float* __restrict__ eps,
    const float* __restrict__ w_router, const float* __restrict__ b_router,
    const float* __restrict__ w_noise, const float* __restrict__ b_noise,
    float* __restrict__ out_router, float* __restrict__ out_idx,
    const int* __restrict__ flags, int cap)
{
    __shared__ double smR[4][64];
    __shared__ double smN[4][64];
    __shared__ double noisy[64];
    const int tid  = threadIdx.x;
    const int lane = tid & 63;      // expert
    const int qw   = tid >> 6;      // K quarter

    int count = flags[0];
    if (count > cap) count = cap;

    for (int i = blockIdx.x; i < count; i += gridDim.x) {
        int tok = flags[2 + i];
        const float4* xr4 = (const float4*)(x + (size_t)tok * D + qw * 512);
        const float* wrB = w_router + (size_t)(qw * 512) * E + lane;
        const float* wnB = w_noise  + (size_t)(qw * 512) * E + lane;

        double pr0 = 0, pr1 = 0, pr2 = 0, pr3 = 0;
        double pn0 = 0, pn1 = 0, pn2 = 0, pn3 = 0;
#pragma unroll 4
        for (int it = 0; it < 128; ++it) {
            float4 xv = xr4[it];
            const float* wr = wrB + (size_t)(it * 4) * E;
            const float* wn = wnB + (size_t)(it * 4) * E;
            pr0 += (double)xv.x * (double)wr[0];
            pr1 += (double)xv.y * (double)wr[E];
            pr2 += (double)xv.z * (double)wr[2 * E];
            pr3 += (double)xv.w * (double)wr[3 * E];
            pn0 += (double)xv.x * (double)wn[0];
            pn1 += (double)xv.y * (double)wn[E];
            pn2 += (double)xv.z * (double)wn[2 * E];
            pn3 += (double)xv.w * (double)wn[3 * E];
        }
        smR[qw][lane] = (pr0 + pr1) + (pr2 + pr3);
        smN[qw][lane] = (pn0 + pn1) + (pn2 + pn3);
        __syncthreads();

        if (tid < 64) {
            double lgv = smR[0][tid] + smR[1][tid] + smR[2][tid] + smR[3][tid] + (double)b_router[tid];
            double nl  = smN[0][tid] + smN[1][tid] + smN[2][tid] + smN[3][tid] + (double)b_noise[tid];
            double sp  = fmax(nl, 0.0) + log1p(exp(-fabs(nl)));
            noisy[tid] = lgv + (double)eps[(size_t)tok * E + tid] * sp;
        }
        __syncthreads();

        if (tid == 0) {
            double tmp[64];
            for (int j = 0; j < 64; ++j) tmp[j] = noisy[j];
            double vals[8]; int idxs[8];
            for (int p = 0; p < 8; ++p) {
                double best = -1e300; int bi = 0;
                for (int j = 0; j < 64; ++j)
                    if (tmp[j] > best) { best = tmp[j]; bi = j; }
                vals[p] = best; idxs[p] = bi; tmp[bi] = -1e300;
            }
            double mx = vals[0], s = 0.0, g[8];
            for (int p = 0; p < 8; ++p) { g[p] = exp(vals[p] - mx); s += g[p]; }
            float rowv[64];
            for (int j = 0; j < 64; ++j) rowv[j] = 0.f;
            for (int p = 0; p < 8; ++p) rowv[idxs[p]] = (float)(g[p] / s);
            for (int j = 0; j < 64; ++j) out_router[(size_t)tok * E + j] = rowv[j];
            for (int p = 0; p < 8; ++p) out_idx[(size_t)tok * TOPK + p] = (float)idxs[p];
        }
        __syncthreads();
    }
}

extern "C" void kernel_launch(void* const* d_in, const int* in_sizes, int n_in,
                              void* d_out, int out_size, void* d_ws, size_t ws_size,
                              hipStream_t stream) {
    const float* x        = (const float*)d_in[0];
    const float* eps      = (const float*)d_in[1];
    const float* w_router = (const float*)d_in[2];
    const float* b_router = (const float*)d_in[3];
    const float* w_noise  = (const float*)d_in[4];
    const float* b_noise  = (const float*)d_in[5];
    const float* w_skip   = (const float*)d_in[6];
    const float* b_skip   = (const float*)d_in[7];

    float* out = (float*)d_out;
    float* out_router = out;                           // 32768*64
    float* out_idx    = out + (size_t)NTOK * E;        // 32768*8
    float* out_skip   = out_idx + (size_t)NTOK * TOPK; // 32768

    char* wbf  = (char*)d_ws;
    int* flags = (int*)((char*)d_ws + FLAGS_OFF);

    int cap = 0;
    if (ws_size > FLAGS_OFF + 16) {
        size_t c = (ws_size - FLAGS_OFF - 8) / 4;
        cap = (c > 16384) ? 16384 : (int)c;
    }

    convert_w_kernel<<<dim3(128), dim3(256), 0, stream>>>(w_router, w_noise, wbf);
    hipMemsetAsync((char*)d_ws + FLAGS_OFF, 0, 8, stream);

    router32_kernel<<<dim3(NBLK2), dim3(BLOCK), 0, stream>>>(
        x, wbf, w_skip, eps, b_router, b_noise, b_skip,
        out_router, out_idx, out_skip, flags, cap);

    fixup_kernel<<<dim3(8192), dim3(256), 0, stream>>>(
        x, eps, w_router, b_router, w_noise, b_noise,
        out_router, out_idx, flags, cap);
}